// Round 4
// baseline (208.712 us; speedup 1.0000x reference)
//
#include <hip/hip_runtime.h>
#include <hip/hip_cooperative_groups.h>

namespace cg = cooperative_groups;

// Problem constants (reference: B=8, T=2000, N=2048, penalty=10.0)
#define B_CONST 8
#define T_CONST 2000
#define N_CONST 2048
#define ZC 40                 // time chunks; grid (4,8,40)=1280 blocks = 5/CU exactly
#define TC (T_CONST / ZC)     // 50 timesteps per thread
#define PENALTY 10.0f

// Partial per (b, n, chunk) packed in float2:
//   .x bits = (cnt << 22) | (t_first << 11) | t_last   (cnt<=50, times<2048)
//   .y      = sum ISI^2                                 (< 2^24, exact fp32)
// Monoid combine (time-ordered): if both nonempty, s2 += (R.first - L.last)^2.
// All quantities are exact in fp32 for any chunking -> matches reference per (b,n).

__global__ __launch_bounds__(128) void cv_fused_kernel(const float* __restrict__ x,
                                                       const float* __restrict__ tcv,
                                                       float2* __restrict__ ws,
                                                       float* __restrict__ out) {
    // ---------------- phase 1: scan my (b, n-slab, t-chunk) ----------------
    const int tid = threadIdx.x;
    const int bx  = blockIdx.x;
    const int b   = blockIdx.y;
    const int z   = blockIdx.z;

    if (tid == 0 && bx == 0 && b == 0 && z == 0) *out = 0.0f;  // ordered by grid.sync

    const int n0 = bx * 512 + tid * 4;   // 4 consecutive n per thread
    const int t0 = z * TC;

    const float* p = x + ((size_t)b * T_CONST + t0) * (size_t)N_CONST + n0;

    float cnt[4]  = {0.f, 0.f, 0.f, 0.f};
    float frst[4] = {0.f, 0.f, 0.f, 0.f};
    float last[4] = {0.f, 0.f, 0.f, 0.f};
    float s2[4]   = {0.f, 0.f, 0.f, 0.f};

#pragma unroll 10
    for (int i = 0; i < TC; ++i) {
        const float4 v = *reinterpret_cast<const float4*>(p);
        p += N_CONST;
        const float t = (float)(t0 + i);
        const float vv[4] = {v.x, v.y, v.z, v.w};
#pragma unroll
        for (int j = 0; j < 4; ++j) {               // branchless: selects only
            const bool sp  = vv[j] > 0.0f;
            const bool has = cnt[j] > 0.0f;
            const float d  = t - last[j];
            s2[j]  += (sp && has) ? d * d : 0.0f;
            frst[j] = (sp && !has) ? t : frst[j];
            last[j] = sp ? t : last[j];
            cnt[j] += sp ? 1.0f : 0.0f;
        }
    }

    float2* w = ws + ((size_t)(b * ZC + z) * N_CONST) + n0;
#pragma unroll
    for (int j = 0; j < 4; ++j) {
        const unsigned meta = ((unsigned)cnt[j] << 22) |
                              ((unsigned)frst[j] << 11) |
                               (unsigned)last[j];
        w[j] = make_float2(__uint_as_float(meta), s2[j]);
    }

    // ---------------- grid-wide barrier (release/acquire) ----------------
    cg::this_grid().sync();

    // ---------------- phase 2: merge 40 chunks per (b,n), loss, reduce ----
    const int bid  = blockIdx.x + gridDim.x * (blockIdx.y + gridDim.y * blockIdx.z);
    if (bid >= (B_CONST * N_CONST) / 128) return;   // only first 128 blocks active

    const int gid = bid * 128 + tid;                // 0 .. B*N-1
    const int bb  = gid >> 11;                      // / N_CONST
    const int n   = gid & (N_CONST - 1);

    float mc = 0.f, mf = 0.f, ml = 0.f, ms = 0.f;
    const float2* base = ws + ((size_t)bb * ZC * N_CONST) + n;
#pragma unroll
    for (int q = 0; q < ZC; ++q) {
        const float2 pp = base[(size_t)q * N_CONST];    // coalesced 512B per wave
        const unsigned meta = __float_as_uint(pp.x);
        const float pc = (float)(meta >> 22);
        const float pf = (float)((meta >> 11) & 2047u);
        const float pl = (float)(meta & 2047u);
        const bool hp = pc > 0.0f;
        const bool hm = mc > 0.0f;
        const float d  = pf - ml;
        const float m2 = ms + pp.y + d * d;
        ms  = hp ? (hm ? m2 : pp.y) : ms;
        mf  = (hp && !hm) ? pf : mf;
        ml  = hp ? pl : ml;
        mc += hp ? pc : 0.0f;
    }

    float cvs;
    if (mc >= 3.0f) {                    // count>=3 implies mean_isi>0 (integer times)
        const float k    = mc - 1.0f;
        const float mean = (ml - mf) / k;              // telescoped sum of ISIs
        const float var  = fmaxf((ms - k * mean * mean) / (k - 1.0f), 0.0f);
        cvs = sqrtf(var) / mean;
    } else {
        cvs = PENALTY;
    }
    const float dd = cvs - tcv[n];
    float e = dd * dd;

    // wave64 shuffle reduce, cross-wave via LDS, one atomic per active block
#pragma unroll
    for (int o = 32; o > 0; o >>= 1) e += __shfl_down(e, o, 64);
    __shared__ float wred[2];
    if ((tid & 63) == 0) wred[tid >> 6] = e;
    __syncthreads();
    if (tid == 0)
        atomicAdd(out, (wred[0] + wred[1]) * (1.0f / ((float)B_CONST * (float)N_CONST)));
}

extern "C" void kernel_launch(void* const* d_in, const int* in_sizes, int n_in,
                              void* d_out, int out_size, void* d_ws, size_t ws_size,
                              hipStream_t stream) {
    const float* x   = (const float*)d_in[0];   // (B,T,N) fp32
    const float* tcv = (const float*)d_in[1];   // (N,) fp32
    float* out  = (float*)d_out;
    float2* ws  = (float2*)d_ws;                // needs B*ZC*N*8 = 5.24 MB

    void* args[] = {(void*)&x, (void*)&tcv, (void*)&ws, (void*)&out};
    hipLaunchCooperativeKernel((void*)cv_fused_kernel,
                               dim3(N_CONST / 512, B_CONST, ZC),  // (4,8,40) = 1280
                               dim3(128), args, 0, stream);
}

// Round 5
// 33.712 us; speedup vs baseline: 6.1910x; 6.1910x over previous
//
#include <hip/hip_runtime.h>

// Problem constants (reference: B=8, T=2000, N=2048, penalty=10.0)
#define B_CONST 8
#define T_CONST 2000
#define N_CONST 2048
#define ZC 40                 // time chunks; grid (4,8,40)=1280 blocks = 5/CU exactly
#define TC (T_CONST / ZC)     // 50 timesteps per thread
#define CPW (ZC / 4)          // 10 chunks merged per wave in kernel 2
#define PENALTY 10.0f

// Partial per (b, n, chunk) packed in float2 (8 B):
//   .x bits = (cnt << 22) | (t_first << 11) | t_last   (cnt<=50, times<2048)
//   .y      = sum ISI^2                                 (< 2^24, exact fp32)
// Monoid combine (time-ordered): if both nonempty, s2 += (R.first - L.last)^2.
// All quantities are integers / exact fp32 sums -> matches reference per (b,n).

__global__ __launch_bounds__(128) void cv_partial_kernel(const float* __restrict__ x,
                                                         float2* __restrict__ ws,
                                                         float* __restrict__ out) {
    // fold d_out zero-init here (saves a dispatch); kernel 2 is stream-ordered after us
    if (threadIdx.x == 0 && blockIdx.x == 0 && blockIdx.y == 0 && blockIdx.z == 0)
        *out = 0.0f;

    const int n0 = blockIdx.x * 512 + threadIdx.x * 4;  // 4 consecutive n per thread
    const int b  = blockIdx.y;
    const int z  = blockIdx.z;
    const int t0 = z * TC;

    const float* p = x + ((size_t)b * T_CONST + t0) * (size_t)N_CONST + n0;

    float cnt[4]  = {0.f, 0.f, 0.f, 0.f};
    float frst[4] = {0.f, 0.f, 0.f, 0.f};
    float last[4] = {0.f, 0.f, 0.f, 0.f};
    float s2[4]   = {0.f, 0.f, 0.f, 0.f};

#pragma unroll 10
    for (int i = 0; i < TC; ++i) {
        const float4 v = *reinterpret_cast<const float4*>(p);
        p += N_CONST;
        const float t = (float)(t0 + i);
        const float vv[4] = {v.x, v.y, v.z, v.w};
#pragma unroll
        for (int j = 0; j < 4; ++j) {               // branchless: selects only
            const bool sp  = vv[j] > 0.0f;
            const bool has = cnt[j] > 0.0f;
            const float d  = t - last[j];
            s2[j]  += (sp && has) ? d * d : 0.0f;
            frst[j] = (sp && !has) ? t : frst[j];
            last[j] = sp ? t : last[j];
            cnt[j] += sp ? 1.0f : 0.0f;
        }
    }

    // pack + store: 4 partials = 32 B = two dwordx4, 32B-aligned
    float4* w = reinterpret_cast<float4*>(ws + ((size_t)(b * ZC + z) * N_CONST) + n0);
    float meta[4];
#pragma unroll
    for (int j = 0; j < 4; ++j) {
        const unsigned m = ((unsigned)cnt[j] << 22) |
                           ((unsigned)frst[j] << 11) |
                            (unsigned)last[j];
        meta[j] = __uint_as_float(m);
    }
    w[0] = make_float4(meta[0], s2[0], meta[1], s2[1]);
    w[1] = make_float4(meta[2], s2[2], meta[3], s2[3]);
}

__global__ __launch_bounds__(256) void cv_final_kernel(const float2* __restrict__ ws,
                                                       const float* __restrict__ tcv,
                                                       float* __restrict__ out) {
    const int l   = threadIdx.x & 63;               // lane -> (b,n) item
    const int w   = threadIdx.x >> 6;               // wave -> chunk segment
    const int gid = blockIdx.x * 64 + l;            // 0 .. B*N-1 (64 divides N)
    const int b   = gid >> 11;
    const int n   = gid & (N_CONST - 1);

    // each wave merges its 10 chunks, branchless so loads pipeline
    float mc = 0.f, mf = 0.f, ml = 0.f, ms = 0.f;
    const float2* base = ws + ((size_t)(b * ZC + w * CPW) * N_CONST) + n;
#pragma unroll
    for (int i = 0; i < CPW; ++i) {
        const float2 pp = base[(size_t)i * N_CONST];    // coalesced 512B per wave
        const unsigned meta = __float_as_uint(pp.x);
        const float pc = (float)(meta >> 22);
        const float pf = (float)((meta >> 11) & 2047u);
        const float pl = (float)(meta & 2047u);
        const bool hp = pc > 0.0f;
        const bool hm = mc > 0.0f;
        const float d  = pf - ml;
        const float m2 = ms + pp.y + d * d;
        ms  = hp ? (hm ? m2 : pp.y) : ms;
        mf  = (hp && !hm) ? pf : mf;
        ml  = hp ? pl : ml;
        mc += hp ? pc : 0.0f;
    }

    __shared__ float4 lds[4][64];
    lds[w][l] = make_float4(mc, mf, ml, ms);
    __syncthreads();

    if (w == 0) {
        mc = 0.f; mf = 0.f; ml = 0.f; ms = 0.f;
#pragma unroll
        for (int q = 0; q < 4; ++q) {               // time-ordered 4-way combine
            const float4 pp = lds[q][l];
            const bool hp = pp.x > 0.0f;
            const bool hm = mc > 0.0f;
            const float d  = pp.y - ml;
            const float m2 = ms + pp.w + d * d;
            ms  = hp ? (hm ? m2 : pp.w) : ms;
            mf  = (hp && !hm) ? pp.y : mf;
            ml  = hp ? pp.z : ml;
            mc += hp ? pp.x : 0.0f;
        }

        float cvs;
        if (mc >= 3.0f) {                 // count>=3 implies mean_isi>0 (integer times)
            const float k    = mc - 1.0f;
            const float mean = (ml - mf) / k;          // telescoped sum of ISIs
            const float var  = fmaxf((ms - k * mean * mean) / (k - 1.0f), 0.0f);
            cvs = sqrtf(var) / mean;
        } else {
            cvs = PENALTY;
        }
        const float dd = cvs - tcv[n];
        float e = dd * dd;

#pragma unroll
        for (int o = 32; o > 0; o >>= 1) e += __shfl_down(e, o, 64);
        if (l == 0)
            atomicAdd(out, e * (1.0f / ((float)B_CONST * (float)N_CONST)));
    }
}

extern "C" void kernel_launch(void* const* d_in, const int* in_sizes, int n_in,
                              void* d_out, int out_size, void* d_ws, size_t ws_size,
                              hipStream_t stream) {
    const float* x   = (const float*)d_in[0];   // (B,T,N) fp32
    const float* tcv = (const float*)d_in[1];   // (N,) fp32
    float* out  = (float*)d_out;
    float2* ws  = (float2*)d_ws;                // needs B*ZC*N*8 = 5.24 MB

    dim3 g1(N_CONST / 512, B_CONST, ZC);        // (4, 8, 40) = 1280 blocks = 5/CU
    cv_partial_kernel<<<g1, dim3(128), 0, stream>>>(x, ws, out);

    cv_final_kernel<<<(B_CONST * N_CONST) / 64, dim3(256), 0, stream>>>(ws, tcv, out);
}